// Round 7
// baseline (35.028 us; speedup 1.0000x reference)
//
#include <hip/hip_runtime.h>

typedef __attribute__((ext_vector_type(8))) short short8;
typedef __attribute__((ext_vector_type(4))) float f32x4;

#define C_COUPLING 1.0f
#define JCH 128          // j-chunk per block (4 tiles of 32)
#define TILE_J 32

#define WAITVM(n) do { asm volatile("s_waitcnt vmcnt(" #n ")" ::: "memory"); \
                       __builtin_amdgcn_sched_barrier(0); } while (0)
#define SB0() __builtin_amdgcn_sched_barrier(0)

// float -> bf16 bits (round-to-nearest-ish; inputs finite, |v|<=1)
__device__ __forceinline__ short f2bf(float f) {
  unsigned u = __builtin_bit_cast(unsigned, f);
  return (short)((u + 0x8000u) >> 16);
}

// T[b][c][j]: c in [0,8) = sin(theta[b,j,c]); c in [8,16) = cos(theta[b,j,c-8])
__global__ __launch_bounds__(128) void vk_prep(const float* __restrict__ th,
                                               unsigned short* __restrict__ T,
                                               int N, int total) {
  int idx = blockIdx.x * blockDim.x + threadIdx.x;   // b*N + j
  if (idx >= total) return;
  const int b = idx / N, j = idx - b * N;
  const float4 t0 = *(const float4*)(th + (size_t)idx * 8);
  const float4 t1 = *(const float4*)(th + (size_t)idx * 8 + 4);
  const float v[8] = {t0.x, t0.y, t0.z, t0.w, t1.x, t1.y, t1.z, t1.w};
  unsigned short* Tb = T + (size_t)b * 16 * N + j;
  #pragma unroll
  for (int d = 0; d < 8; ++d) {
    Tb[(size_t)d * N]       = (unsigned short)f2bf(__sinf(v[d]));
    Tb[(size_t)(d + 8) * N] = (unsigned short)f2bf(__cosf(v[d]));
  }
}

// out = gamma + (C/N)*coupling  (theta + DT*ATTR*(gamma-theta) == gamma)
// P = (A.*cos(alpha)) x [sin|cos](theta), Q = (A.*sin(alpha)) x [sin|cos](theta)
// coupling(i,d) = c_i*(P[d]-Q[d+8]) - s_i*(P[d+8]+Q[d])
__global__ __launch_bounds__(256, 4) void vk_main(
    const float* __restrict__ theta,
    const float* __restrict__ gamma,
    const float* __restrict__ affinity,
    const float* __restrict__ alpha,
    const unsigned short* __restrict__ T,
    float* __restrict__ out,
    int N, int jsCnt) {
  const int jc = blockIdx.x % jsCnt;
  int t = blockIdx.x / jsCnt;
  const int nib = N >> 6;
  const int ib = t % nib;
  const int b = t / nib;
  const int j0 = jc * JCH;

  const int wave = threadIdx.x >> 6;
  const int lane = threadIdx.x & 63;
  const int itile = ib * 4 + wave;
  const int g = lane >> 4;           // k-group 0..3
  const int col = lane & 15;         // A row (M) / B col (N) index
  const int arow = itile * 16 + col;

  const float* __restrict__ Arow = affinity + ((size_t)b * N + arow) * (size_t)N + j0;
  const float* __restrict__ Lrow = alpha    + ((size_t)b * N + arow) * (size_t)N + j0;
  const unsigned short* __restrict__ Trow = T + ((size_t)b * 16 + col) * (size_t)N + j0;

  // ---- epilogue prefetch: OLDEST 8 loads in the VMEM queue ----
  const int irow0 = itile * 16 + g * 4;
  const size_t obase = (((size_t)b * N + irow0) << 3) + (col & 7);
  const float tl0 = theta[obase];
  const float tl1 = theta[obase + 8];
  const float tl2 = theta[obase + 16];
  const float tl3 = theta[obase + 24];
  const float gv0 = gamma[obase];
  const float gv1 = gamma[obase + 8];
  const float gv2 = gamma[obase + 16];
  const float gv3 = gamma[obase + 24];
  SB0();

  // ---- all 4 tiles' loads issued up front: 5 loads per tile ----
  const int o = g * 8;
#define TLOAD(p, jt) \
  const float4 ax##p = *(const float4*)(Arow + (jt) + o); \
  const float4 ay##p = *(const float4*)(Arow + (jt) + o + 4); \
  const float4 lx##p = *(const float4*)(Lrow + (jt) + o); \
  const float4 ly##p = *(const float4*)(Lrow + (jt) + o + 4); \
  const short8 bf##p = *(const short8*)(Trow + (jt) + o);
  TLOAD(0, 0)  SB0();
  TLOAD(1, TILE_J)  SB0();
  TLOAD(2, 2 * TILE_J)  SB0();
  TLOAD(3, 3 * TILE_J)  SB0();
#undef TLOAD

  f32x4 P = {0.f, 0.f, 0.f, 0.f};
  f32x4 Q = {0.f, 0.f, 0.f, 0.f};

#define COMPUTE(p) do { \
    const float av[8] = {ax##p.x, ax##p.y, ax##p.z, ax##p.w, \
                         ay##p.x, ay##p.y, ay##p.z, ay##p.w}; \
    const float lv[8] = {lx##p.x, lx##p.y, lx##p.z, lx##p.w, \
                         ly##p.x, ly##p.y, ly##p.z, ly##p.w}; \
    short8 wc, ws; \
    _Pragma("unroll") \
    for (int k = 0; k < 8; ++k) { \
      const float sv = __sinf(lv[k]); \
      const float cv = __cosf(lv[k]); \
      wc[k] = f2bf(av[k] * cv); \
      ws[k] = f2bf(av[k] * sv); \
    } \
    P = __builtin_amdgcn_mfma_f32_16x16x32_bf16(wc, bf##p, P, 0, 0, 0); \
    Q = __builtin_amdgcn_mfma_f32_16x16x32_bf16(ws, bf##p, Q, 0, 0, 0); \
  } while (0)

  WAITVM(15);   // tile 0 landed (tiles 1-3 = 15 ops still outstanding)
  COMPUTE(0);
  WAITVM(10);
  COMPUTE(1);
  WAITVM(5);
  COMPUTE(2);
  WAITVM(0);
  COMPUTE(3);
#undef COMPUTE

  // C/D layout: col = lane&15, row = (lane>>4)*4 + reg  [m89]
  float pc[4], qc[4];
  #pragma unroll
  for (int r = 0; r < 4; ++r) {
    pc[r] = __shfl_xor(P[r], 8, 64);
    qc[r] = __shfl_xor(Q[r], 8, 64);
  }
  if (col < 8) {
    const float sc = C_COUPLING / (float)N;
    const float gsel = (jc == 0) ? 1.0f : 0.0f;
    const float tl[4] = {tl0, tl1, tl2, tl3};
    const float gv[4] = {gv0, gv1, gv2, gv3};
    #pragma unroll
    for (int r = 0; r < 4; ++r) {
      const float sv = __sinf(tl[r]);
      const float cv = __cosf(tl[r]);
      float coup = sc * (cv * (P[r] - qc[r]) - sv * (pc[r] + Q[r]));
      coup += gsel * gv[r];               // fold drive term once (jc==0)
      unsafeAtomicAdd(out + obase + 8 * r, coup);
    }
  }
}

extern "C" void kernel_launch(void* const* d_in, const int* in_sizes, int n_in,
                              void* d_out, int out_size, void* d_ws, size_t ws_size,
                              hipStream_t stream) {
  const float* theta = (const float*)d_in[0];
  const float* gamma = (const float*)d_in[1];
  const float* aff   = (const float*)d_in[2];
  const float* alp   = (const float*)d_in[3];
  float* out = (float*)d_out;
  unsigned short* T = (unsigned short*)d_ws;   // B*16*N bf16 = 256 KB

  const long t0 = in_sizes[0];              // B*N*D (D=8)
  const long t2 = in_sizes[2];              // B*N*N
  const int N = (int)(8 * t2 / t0);
  const int B = (int)(t0 / ((long)N * 8));

  hipMemsetAsync(out, 0, (size_t)out_size * sizeof(float), stream);

  const int bn = B * N;
  vk_prep<<<dim3((bn + 127) / 128), dim3(128), 0, stream>>>(theta, T, N, bn);

  const int js = N / JCH;                   // 16 for N=2048
  dim3 grid(B * (N / 64) * js);             // 2048 blocks
  vk_main<<<grid, dim3(256), 0, stream>>>(theta, gamma, aff, alp, T, out, N, js);
}

// Round 9
// 34.700 us; speedup vs baseline: 1.0095x; 1.0095x over previous
//
#include <hip/hip_runtime.h>

typedef __attribute__((ext_vector_type(8))) short short8;
typedef __attribute__((ext_vector_type(4))) float f32x4;

#define C_COUPLING 1.0f
#define JBLK 256         // j-extent per block (one staged tile)
#define SB0() __builtin_amdgcn_sched_barrier(0)

typedef __attribute__((address_space(3))) unsigned lds_u32;
typedef __attribute__((address_space(1))) const unsigned g_u32;

__device__ __forceinline__ void gl_lds16(const float* g, void* l) {
  // 16B/lane: per-lane global src -> LDS wave-uniform base + lane*16
  __builtin_amdgcn_global_load_lds((g_u32*)g, (lds_u32*)l, 16, 0, 0);
}

// float -> bf16 bits (round-to-nearest-ish; inputs finite, |v|<=1)
__device__ __forceinline__ short f2bf(float f) {
  unsigned u = __builtin_bit_cast(unsigned, f);
  return (short)((u + 0x8000u) >> 16);
}

// T[b][c][j]: c in [0,8) = sin(theta[b,j,c]); c in [8,16) = cos(theta[b,j,c-8])
__global__ __launch_bounds__(128) void vk_prep(const float* __restrict__ th,
                                               unsigned short* __restrict__ T,
                                               int N, int total) {
  int idx = blockIdx.x * blockDim.x + threadIdx.x;   // b*N + j
  if (idx >= total) return;
  const int b = idx / N, j = idx - b * N;
  const float4 t0 = *(const float4*)(th + (size_t)idx * 8);
  const float4 t1 = *(const float4*)(th + (size_t)idx * 8 + 4);
  const float v[8] = {t0.x, t0.y, t0.z, t0.w, t1.x, t1.y, t1.z, t1.w};
  unsigned short* Tb = T + (size_t)b * 16 * N + j;
  #pragma unroll
  for (int d = 0; d < 8; ++d) {
    Tb[(size_t)d * N]       = (unsigned short)f2bf(__sinf(v[d]));
    Tb[(size_t)(d + 8) * N] = (unsigned short)f2bf(__cosf(v[d]));
  }
}

// out = gamma + (C/N)*coupling  (theta + DT*ATTR*(gamma-theta) == gamma)
// Block: 16 i-rows x 256 j. Stage A[16][256], L[16][256] via 32x 1KB
// contiguous global_load_lds (XOR chunk-swizzled source, linear LDS dest).
// Wave w computes j-quarter [64w,64w+64) (2 MFMA k-steps); cross-wave
// reduce of P,Q in LDS; wave 0 epilogue + atomics.
// Cross-wave staging => plain __syncthreads() (full fence + vmcnt drain);
// raw s_barrier+counted-vmcnt raced here (R8 lesson).
__global__ __launch_bounds__(256) void vk_main(
    const float* __restrict__ theta,
    const float* __restrict__ gamma,
    const float* __restrict__ affinity,
    const float* __restrict__ alpha,
    const unsigned short* __restrict__ T,
    float* __restrict__ out,
    int N, int jsCnt) {
  __shared__ __align__(16) float lds[8192];   // A: floats [0,4096), L: [4096,8192)

  const int jc = blockIdx.x % jsCnt;
  const int t = blockIdx.x / jsCnt;
  const int nit = N >> 4;
  const int itile = t % nit;
  const int b = t / nit;
  const int i0 = itile << 4;
  const int j0 = jc * JBLK;

  const int tid = threadIdx.x;
  const int wave = tid >> 6, lane = tid & 63;
  const int g = lane >> 4, col = lane & 15;

  // ---- stage: wave w stages rows 4w..4w+3 of A and L; 1KB/instr ----
  // LDS row r chunk p (16B) holds global chunk p ^ (r&7) of that row.
  #pragma unroll
  for (int q = 0; q < 4; ++q) {
    const int r = wave * 4 + q;
    const size_t rowoff = ((size_t)b * N + i0 + r) * (size_t)N + j0;
    const int c = (lane ^ (r & 7)) << 2;      // float offset of swizzled chunk
    gl_lds16(affinity + rowoff + c, &lds[r * 256]);
    gl_lds16(alpha    + rowoff + c, &lds[4096 + r * 256]);
  }
  SB0();

  // ---- B-fragment loads (L2-resident T table), kk = 0,1 ----
  const unsigned short* Trow =
      T + ((size_t)b * 16 + col) * (size_t)N + j0 + wave * 64 + g * 8;
  const short8 bf0 = *(const short8*)(Trow);
  const short8 bf1 = *(const short8*)(Trow + 32);
  SB0();

  // ---- epilogue prefetch ----
  const size_t obase = (((size_t)b * N + i0 + g * 4) << 3) + (col & 7);
  const float tl0 = theta[obase],      tl1 = theta[obase + 8];
  const float tl2 = theta[obase + 16], tl3 = theta[obase + 24];
  const float gv0 = gamma[obase],      gv1 = gamma[obase + 8];
  const float gv2 = gamma[obase + 16], gv3 = gamma[obase + 24];

  __syncthreads();     // full fence: all waves' stages visible to all

  f32x4 P = {0.f, 0.f, 0.f, 0.f};
  f32x4 Q = {0.f, 0.f, 0.f, 0.f};
  const int s = col & 7;
  const float* Ar = &lds[col * 256];

  #pragma unroll
  for (int kk = 0; kk < 2; ++kk) {
    const int c0 = wave * 16 + kk * 8 + 2 * g;      // even
    const float4 a_lo = *(const float4*)(Ar + ((c0 ^ s) << 2));
    const float4 a_hi = *(const float4*)(Ar + (((c0 + 1) ^ s) << 2));
    const float4 l_lo = *(const float4*)(Ar + 4096 + ((c0 ^ s) << 2));
    const float4 l_hi = *(const float4*)(Ar + 4096 + (((c0 + 1) ^ s) << 2));
    const float av[8] = {a_lo.x, a_lo.y, a_lo.z, a_lo.w,
                         a_hi.x, a_hi.y, a_hi.z, a_hi.w};
    const float lv[8] = {l_lo.x, l_lo.y, l_lo.z, l_lo.w,
                         l_hi.x, l_hi.y, l_hi.z, l_hi.w};
    short8 wc, ws;
    #pragma unroll
    for (int k = 0; k < 8; ++k) {
      const float sv = __sinf(lv[k]);
      const float cv = __cosf(lv[k]);
      wc[k] = f2bf(av[k] * cv);
      ws[k] = f2bf(av[k] * sv);
    }
    const short8 bf = kk ? bf1 : bf0;
    P = __builtin_amdgcn_mfma_f32_16x16x32_bf16(wc, bf, P, 0, 0, 0);
    Q = __builtin_amdgcn_mfma_f32_16x16x32_bf16(ws, bf, Q, 0, 0, 0);
  }

  // ---- cross-wave reduce of P,Q (reuse A-buffer rows 0-7) ----
  __syncthreads();     // all staged-data reads consumed before overwrite
  *(f32x4*)&lds[wave * 256 + lane * 4] = P;             // floats [0,1024)
  *(f32x4*)&lds[1024 + wave * 256 + lane * 4] = Q;      // floats [1024,2048)
  __syncthreads();

  if (wave == 0) {
    f32x4 Ps = {0.f, 0.f, 0.f, 0.f};
    f32x4 Qs = {0.f, 0.f, 0.f, 0.f};
    #pragma unroll
    for (int w2 = 0; w2 < 4; ++w2) {
      Ps += *(const f32x4*)&lds[w2 * 256 + lane * 4];
      Qs += *(const f32x4*)&lds[1024 + w2 * 256 + lane * 4];
    }
    // C/D layout: col = lane&15, row = (lane>>4)*4 + reg  [m89]
    float pc[4], qc[4];
    #pragma unroll
    for (int r = 0; r < 4; ++r) {
      pc[r] = __shfl_xor(Ps[r], 8, 64);
      qc[r] = __shfl_xor(Qs[r], 8, 64);
    }
    if (col < 8) {
      const float sc = C_COUPLING / (float)N;
      const float gsel = (jc == 0) ? 1.0f : 0.0f;
      const float tl[4] = {tl0, tl1, tl2, tl3};
      const float gv[4] = {gv0, gv1, gv2, gv3};
      #pragma unroll
      for (int r = 0; r < 4; ++r) {
        const float sv = __sinf(tl[r]);
        const float cv = __cosf(tl[r]);
        float coup = sc * (cv * (Ps[r] - qc[r]) - sv * (pc[r] + Qs[r]));
        coup += gsel * gv[r];              // fold drive term once (jc==0)
        unsafeAtomicAdd(out + obase + 8 * r, coup);
      }
    }
  }
}

extern "C" void kernel_launch(void* const* d_in, const int* in_sizes, int n_in,
                              void* d_out, int out_size, void* d_ws, size_t ws_size,
                              hipStream_t stream) {
  const float* theta = (const float*)d_in[0];
  const float* gamma = (const float*)d_in[1];
  const float* aff   = (const float*)d_in[2];
  const float* alp   = (const float*)d_in[3];
  float* out = (float*)d_out;
  unsigned short* T = (unsigned short*)d_ws;   // B*16*N bf16 = 256 KB

  const long t0 = in_sizes[0];              // B*N*D (D=8)
  const long t2 = in_sizes[2];              // B*N*N
  const int N = (int)(8 * t2 / t0);
  const int B = (int)(t0 / ((long)N * 8));

  hipMemsetAsync(out, 0, (size_t)out_size * sizeof(float), stream);

  const int bn = B * N;
  vk_prep<<<dim3((bn + 127) / 128), dim3(128), 0, stream>>>(theta, T, N, bn);

  const int js = N / JBLK;                  // 8 for N=2048
  dim3 grid(B * (N / 16) * js);             // 4096 blocks
  vk_main<<<grid, dim3(256), 0, stream>>>(theta, gamma, aff, alp, T, out, N, js);
}

// Round 10
// 31.063 us; speedup vs baseline: 1.1277x; 1.1171x over previous
//
#include <hip/hip_runtime.h>

typedef __attribute__((ext_vector_type(8))) short short8;
typedef __attribute__((ext_vector_type(4))) float f32x4;

#define C_COUPLING 1.0f
#define TPITCH 2056   // shorts per T row: 2048 + 8 pad (4112 B) -> spread banks

// float -> bf16 bits (round-to-nearest-ish; inputs finite, |v|<=1)
__device__ __forceinline__ unsigned short f2bf(float f) {
  unsigned u = __builtin_bit_cast(unsigned, f);
  return (unsigned short)((u + 0x8000u) >> 16);
}

// One block = (b, 16 i-rows). 8 waves = 8 j-chunks of N/8.
// LDS trig table T[c][j] (c<8: sin(theta[b,j,c]); c>=8: cos), full N width.
// P = (A.*cos(alpha)) x [sin|cos], Q = (A.*sin(alpha)) x [sin|cos].
// coupling(i,d) = c_i*(P[d]-Q[d+8]) - s_i*(P[d+8]+Q[d])
// out = gamma + (C/N)*coupling   (theta + DT*ATTR*(gamma-theta) == gamma)
__global__ __launch_bounds__(512) void vk_fused(
    const float* __restrict__ theta,
    const float* __restrict__ gamma,
    const float* __restrict__ affinity,
    const float* __restrict__ alpha,
    float* __restrict__ out,
    int N) {
  __shared__ __align__(16) unsigned short T[16 * TPITCH];   // 65792 B

  const int nit = N >> 4;
  const int itile = blockIdx.x % nit;
  const int b = blockIdx.x / nit;
  const int i0 = itile << 4;

  const int tid = threadIdx.x;
  const int wave = tid >> 6, lane = tid & 63;
  const int g = lane >> 4, col = lane & 15;

  // ---- build trig table (4 consecutive j per thread per trip) ----
  {
    const int nj4 = N >> 2;
    for (int j4 = tid; j4 < nj4; j4 += 512) {
      const float* tp = theta + ((size_t)b * N + 4 * (size_t)j4) * 8;
      float v[4][8];
      #pragma unroll
      for (int jj = 0; jj < 4; ++jj) {
        const float4 x = *(const float4*)(tp + jj * 8);
        const float4 y = *(const float4*)(tp + jj * 8 + 4);
        v[jj][0] = x.x; v[jj][1] = x.y; v[jj][2] = x.z; v[jj][3] = x.w;
        v[jj][4] = y.x; v[jj][5] = y.y; v[jj][6] = y.z; v[jj][7] = y.w;
      }
      #pragma unroll
      for (int d = 0; d < 8; ++d) {
        const unsigned s0 = (unsigned)f2bf(__sinf(v[0][d])) |
                            ((unsigned)f2bf(__sinf(v[1][d])) << 16);
        const unsigned s1 = (unsigned)f2bf(__sinf(v[2][d])) |
                            ((unsigned)f2bf(__sinf(v[3][d])) << 16);
        const unsigned c0 = (unsigned)f2bf(__cosf(v[0][d])) |
                            ((unsigned)f2bf(__cosf(v[1][d])) << 16);
        const unsigned c1 = (unsigned)f2bf(__cosf(v[2][d])) |
                            ((unsigned)f2bf(__cosf(v[3][d])) << 16);
        *(uint2*)&T[d * TPITCH + 4 * j4]       = make_uint2(s0, s1);
        *(uint2*)&T[(8 + d) * TPITCH + 4 * j4] = make_uint2(c0, c1);
      }
    }
  }
  __syncthreads();

  // ---- j-loop: wave handles j-chunk [j0, j0 + N/8) ----
  const int jch = N >> 3;
  const int j0 = wave * jch;
  const int o = g * 8;
  const float* __restrict__ Arow =
      affinity + ((size_t)b * N + i0 + col) * (size_t)N + j0;
  const float* __restrict__ Lrow =
      alpha    + ((size_t)b * N + i0 + col) * (size_t)N + j0;
  const unsigned short* Trow = T + col * TPITCH + j0;

  f32x4 P = {0.f, 0.f, 0.f, 0.f};
  f32x4 Q = {0.f, 0.f, 0.f, 0.f};

  #pragma unroll 2
  for (int jt = 0; jt < jch; jt += 32) {
    const float4 a0 = *(const float4*)(Arow + jt + o);
    const float4 a1 = *(const float4*)(Arow + jt + o + 4);
    const float4 l0 = *(const float4*)(Lrow + jt + o);
    const float4 l1 = *(const float4*)(Lrow + jt + o + 4);
    const short8 bf = *(const short8*)(Trow + jt + o);   // LDS b128
    const float av[8] = {a0.x, a0.y, a0.z, a0.w, a1.x, a1.y, a1.z, a1.w};
    const float lv[8] = {l0.x, l0.y, l0.z, l0.w, l1.x, l1.y, l1.z, l1.w};
    short8 wc, ws;
    #pragma unroll
    for (int k = 0; k < 8; ++k) {
      const float sv = __sinf(lv[k]);
      const float cv = __cosf(lv[k]);
      wc[k] = (short)f2bf(av[k] * cv);
      ws[k] = (short)f2bf(av[k] * sv);
    }
    P = __builtin_amdgcn_mfma_f32_16x16x32_bf16(wc, bf, P, 0, 0, 0);
    Q = __builtin_amdgcn_mfma_f32_16x16x32_bf16(ws, bf, Q, 0, 0, 0);
  }

  // ---- cross-wave reduce through LDS (reuse T region) ----
  __syncthreads();                       // all T reads done
  float* R = (float*)T;
  *(f32x4*)&R[wave * 512 + lane * 8]     = P;
  *(f32x4*)&R[wave * 512 + lane * 8 + 4] = Q;
  __syncthreads();

  if (wave == 0) {
    f32x4 Ps = {0.f, 0.f, 0.f, 0.f};
    f32x4 Qs = {0.f, 0.f, 0.f, 0.f};
    #pragma unroll
    for (int w2 = 0; w2 < 8; ++w2) {
      Ps += *(const f32x4*)&R[w2 * 512 + lane * 8];
      Qs += *(const f32x4*)&R[w2 * 512 + lane * 8 + 4];
    }
    // C/D layout: col = lane&15, row = (lane>>4)*4 + reg  [m89]
    float pc[4], qc[4];
    #pragma unroll
    for (int r = 0; r < 4; ++r) {
      pc[r] = __shfl_xor(Ps[r], 8, 64);
      qc[r] = __shfl_xor(Qs[r], 8, 64);
    }
    if (col < 8) {
      const float sc = C_COUPLING / (float)N;
      const size_t obase = (((size_t)b * N + i0 + g * 4) << 3) + col;
      #pragma unroll
      for (int r = 0; r < 4; ++r) {
        const float thi = theta[obase + 8 * r];
        const float sv = __sinf(thi);
        const float cv = __cosf(thi);
        const float coup = sc * (cv * (Ps[r] - qc[r]) - sv * (pc[r] + Qs[r]));
        out[obase + 8 * r] = gamma[obase + 8 * r] + coup;
      }
    }
  }
}

extern "C" void kernel_launch(void* const* d_in, const int* in_sizes, int n_in,
                              void* d_out, int out_size, void* d_ws, size_t ws_size,
                              hipStream_t stream) {
  const float* theta = (const float*)d_in[0];
  const float* gamma = (const float*)d_in[1];
  const float* aff   = (const float*)d_in[2];
  const float* alp   = (const float*)d_in[3];
  float* out = (float*)d_out;

  const long t0 = in_sizes[0];              // B*N*D (D=8)
  const long t2 = in_sizes[2];              // B*N*N
  const int N = (int)(8 * t2 / t0);
  const int B = (int)(t0 / ((long)N * 8));

  dim3 grid(B * (N / 16));                  // 512 blocks for B=4, N=2048
  vk_fused<<<grid, dim3(512), 0, stream>>>(theta, gamma, aff, alp, out, N);
}